// Round 7
// baseline (1012.228 us; speedup 1.0000x reference)
//
#include <hip/hip_runtime.h>

// ---------------------------------------------------------------------------
// GGNN on MI355X (gfx950). Runtime dtype probe (validated round 4): flags[0]=1
// -> fp32 float tensors + fp32 out; flags[1]=1 -> int64 edge_index.
//
// Round-7 changes:
//   * gather fused into GRU (4 kernels, not 8): register gather with 4-node
//     interleaved uint2 layout (16 lines in flight/wave), LDS-staged agg tile,
//     then MFMA+gates. Removes 25.6 MB/layer aggB round trip. h is now
//     double-buffered (hin read-only per layer -> gather/update race-free).
//   * bucket_csr segment gather parallelized (binary search over seg offsets).
//   * weight-prep launches merged 4 -> 2. Total launches 17 -> 11.
// Math (linearity): segment_sum((h@Wc)[src]) == segment_sum(h[src])@Wc;
//   (agg@Wc)@W_ih^T == agg@(Wc@W_ih^T) =: agg@Wcomb (built on device).
// ---------------------------------------------------------------------------

#define DEVI __device__ __forceinline__

typedef __attribute__((ext_vector_type(8))) short short8;
typedef __attribute__((ext_vector_type(4))) float f32x4;

constexpr int N_NODES   = 100000;
constexpr int F_IN      = 256;
constexpr int H_DIM     = 64;
constexpr int C_OUT     = 40;
constexpr int ROW_TILES = N_NODES / 16;             // 6250
constexpr int CH        = 8192;                     // edges per bucket_local wg
constexpr int NBUCK     = (N_NODES + 127) / 128;    // 782 buckets of 128 nodes
constexpr int LB_STRIDE = NBUCK + 1;                // +1 sentinel (wg total)
constexpr int BCAP      = 2048;                     // max edges/bucket (mean 1534)

DEVI float bf2f(unsigned short u) {
    unsigned v = ((unsigned)u) << 16;
    float f; __builtin_memcpy(&f, &v, 4); return f;
}
DEVI unsigned short f2bf(float f) {
    unsigned u; __builtin_memcpy(&u, &f, 4);
    unsigned r = u + 0x7FFFu + ((u >> 16) & 1u);   // round-to-nearest-even
    return (unsigned short)(r >> 16);
}
DEVI float in_elem(const void* p, size_t idx, int f32flag) {
    return f32flag ? ((const float*)p)[idx]
                   : bf2f(((const unsigned short*)p)[idx]);
}
DEVI short8 f32row_to_frag(const float* __restrict__ p) {
    const f32x4* q = (const f32x4*)p;
    f32x4 lo = q[0], hi = q[1];
    short8 a;
    a[0] = (short)f2bf(lo[0]); a[1] = (short)f2bf(lo[1]);
    a[2] = (short)f2bf(lo[2]); a[3] = (short)f2bf(lo[3]);
    a[4] = (short)f2bf(hi[0]); a[5] = (short)f2bf(hi[1]);
    a[6] = (short)f2bf(hi[2]); a[7] = (short)f2bf(hi[3]);
    return a;
}

// ---------------------------------------------------------------------------
__global__ void detect_kernel(const void* x, const int* ei, int* flags) {
    if (threadIdx.x != 0 || blockIdx.x != 0) return;
    const unsigned short* u = (const unsigned short*)x;
    int sane = 0;
    for (int i = 0; i < 256; ++i) {
        int e = (u[i] >> 7) & 0xFF;
        if (e >= 100 && e <= 145) sane++;
    }
    flags[0] = (sane < 230) ? 1 : 0;
    int zeros = 0;
    for (int i = 0; i < 64; ++i)
        if (ei[2 * i + 1] == 0) zeros++;
    flags[1] = (zeros >= 63) ? 1 : 0;
}

// ======================= CSR build: two-level sort =========================
__global__ __launch_bounds__(256) void bucket_local(
        const int* __restrict__ ei, int E, const int* __restrict__ flags,
        int* __restrict__ wgsorted,     // [nwg*CH]  packed (ldst<<17 | src)
        int* __restrict__ lbase_g) {    // [nwg*LB_STRIDE]
    __shared__ int hist[NBUCK];
    __shared__ int partial[256];
    __shared__ int staging[CH];
    int tid = threadIdx.x, wg = blockIdx.x;
    int i64 = flags[1];
    int base = wg * CH;
    int cnt_wg = min(CH, E - base);

    for (int i = tid; i < NBUCK; i += 256) hist[i] = 0;
    __syncthreads();
    for (int k = tid; k < cnt_wg; k += 256) {
        size_t e = (size_t)base + k;
        int d = i64 ? ei[2 * ((size_t)E + e)] : ei[(size_t)E + e];
        atomicAdd(&hist[d >> 7], 1);
    }
    __syncthreads();
    int i0 = 4 * tid;
    int e0 = (i0 + 0 < NBUCK) ? hist[i0 + 0] : 0;
    int e1 = (i0 + 1 < NBUCK) ? hist[i0 + 1] : 0;
    int e2 = (i0 + 2 < NBUCK) ? hist[i0 + 2] : 0;
    int e3 = (i0 + 3 < NBUCK) ? hist[i0 + 3] : 0;
    int s0 = e0, s1 = s0 + e1, s2 = s1 + e2, s3 = s2 + e3;
    __syncthreads();
    partial[tid] = s3;
    __syncthreads();
    for (int ofs = 1; ofs < 256; ofs <<= 1) {
        int add = (tid >= ofs) ? partial[tid - ofs] : 0;
        __syncthreads();
        partial[tid] += add;
        __syncthreads();
    }
    int pbase = (tid > 0) ? partial[tid - 1] : 0;
    if (i0 + 0 < NBUCK) hist[i0 + 0] = pbase;
    if (i0 + 1 < NBUCK) hist[i0 + 1] = pbase + s0;
    if (i0 + 2 < NBUCK) hist[i0 + 2] = pbase + s1;
    if (i0 + 3 < NBUCK) hist[i0 + 3] = pbase + s2;
    __syncthreads();
    int* lb = lbase_g + (size_t)wg * LB_STRIDE;
    for (int i = tid; i < NBUCK; i += 256) lb[i] = hist[i];
    if (tid == 0) lb[NBUCK] = cnt_wg;
    __syncthreads();
    for (int k = tid; k < cnt_wg; k += 256) {
        size_t e = (size_t)base + k;
        int s, d;
        if (i64) { s = ei[2 * e]; d = ei[2 * ((size_t)E + e)]; }
        else     { s = ei[e];     d = ei[(size_t)E + e]; }
        int pos = atomicAdd(&hist[d >> 7], 1);
        staging[pos] = ((d & 127) << 17) | s;     // src < 2^17
    }
    __syncthreads();
    for (int k = tid; k < cnt_wg; k += 256)
        wgsorted[(size_t)base + k] = staging[k];
}

__global__ __launch_bounds__(256) void bucket_csr(
        const int* __restrict__ wgsorted,
        const int* __restrict__ lbase_g,
        int nwg,
        int* __restrict__ rowptr,
        int* __restrict__ counts,
        int* __restrict__ esrc) {       // [NBUCK*BCAP] padded
    __shared__ int segincl[256];        // inclusive scan of segment counts
    __shared__ int segbase[256];
    __shared__ int edata[BCAP];
    __shared__ int sout[BCAP];
    __shared__ int hist2[128];
    __shared__ int cur2[128];
    int tid = threadIdx.x, b = blockIdx.x;

    int lbv = 0, cntv = 0;
    if (tid < nwg) {
        const int* lb = lbase_g + (size_t)tid * LB_STRIDE;
        lbv  = lb[b];
        cntv = lb[b + 1] - lbv;
    }
    segbase[tid] = lbv;
    segincl[tid] = cntv;
    __syncthreads();
    for (int ofs = 1; ofs < 256; ofs <<= 1) {
        int add = (tid >= ofs) ? segincl[tid - ofs] : 0;
        __syncthreads();
        segincl[tid] += add;
        __syncthreads();
    }
    int tot = min(segincl[255], BCAP);   // 13-sigma margin; clamp = visible-fail
    // parallel segment gather: binary search which segment each slot belongs to
    for (int i = tid; i < tot; i += 256) {
        int lo = 0, hi = 255;
        while (lo < hi) {
            int mid = (lo + hi) >> 1;
            if (segincl[mid] > i) hi = mid; else lo = mid + 1;
        }
        int excl = (lo > 0) ? segincl[lo - 1] : 0;
        edata[i] = wgsorted[(size_t)lo * CH + segbase[lo] + (i - excl)];
    }
    if (tid < 128) hist2[tid] = 0;
    __syncthreads();
    for (int i = tid; i < tot; i += 256) atomicAdd(&hist2[edata[i] >> 17], 1);
    __syncthreads();
    if (tid < 128) cur2[tid] = hist2[tid];
    __syncthreads();
    for (int ofs = 1; ofs < 128; ofs <<= 1) {
        int add = 0;
        if (tid < 128 && tid >= ofs) add = cur2[tid - ofs];
        __syncthreads();
        if (tid < 128) cur2[tid] += add;
        __syncthreads();
    }
    int nodeexcl = 0;
    if (tid < 128) nodeexcl = (tid > 0) ? cur2[tid - 1] : 0;
    __syncthreads();
    if (tid < 128) {
        int node = b * 128 + tid;
        if (node < N_NODES) {
            counts[node] = hist2[tid];
            rowptr[node] = b * BCAP + nodeexcl;
        }
        cur2[tid] = nodeexcl;
    }
    __syncthreads();
    for (int i = tid; i < tot; i += 256) {
        int p = edata[i];
        int pos = atomicAdd(&cur2[p >> 17], 1);
        sout[pos] = p & 0x1FFFF;
    }
    __syncthreads();
    for (int i = tid; i < tot; i += 256)
        esrc[(size_t)b * BCAP + i] = sout[i];
}

// ============================ weight prep ==================================
// merged: winfrag (16384) | wofrag (3072) | whh bf16 copy (12288) | bias (384)
__global__ void prep_misc(const void* __restrict__ w_in,
                          const void* __restrict__ w_out,
                          const void* __restrict__ w_hh,
                          const void* __restrict__ b_ih,
                          const void* __restrict__ b_hh,
                          unsigned short* __restrict__ winfrag,
                          unsigned short* __restrict__ wofrag,
                          unsigned short* __restrict__ whh_c,
                          unsigned short* __restrict__ bias_c,
                          const int* __restrict__ flags) {
    int f32 = flags[0];
    int t = blockIdx.x * blockDim.x + threadIdx.x;
    if (t < 16384) {
        // W_in [256x64] -> B-frag, npad=4
        int i = t & 7, lane = (t >> 3) & 63, jt = (t >> 9) & 3, kb = t >> 11;
        int k = kb * 32 + ((lane >> 4) << 3) + i;
        int col = jt * 16 + (lane & 15);
        winfrag[t] = f2bf(in_elem(w_in, (size_t)k * 64 + col, f32));
    } else if (t < 16384 + 3072) {
        // W_out [64x40] -> B-frag, npad=3, pad cols >= 40
        int u = t - 16384;
        int i = u & 7, lane = (u >> 3) & 63;
        int jt = (u >> 9) % 3, kb = u / 1536;
        int k = kb * 32 + ((lane >> 4) << 3) + i;
        int col = jt * 16 + (lane & 15);
        wofrag[u] = (col < 40) ? f2bf(in_elem(w_out, (size_t)k * 40 + col, f32))
                               : (unsigned short)0;
    } else if (t < 16384 + 3072 + 12288) {
        int u = t - 16384 - 3072;
        whh_c[u] = f2bf(in_elem(w_hh, u, f32));
    } else if (t < 16384 + 3072 + 12288 + 192) {
        int u = t - 16384 - 3072 - 12288;
        bias_c[u] = f2bf(in_elem(b_ih, u, f32));
    } else if (t < 16384 + 3072 + 12288 + 384) {
        int u = t - 16384 - 3072 - 12288 - 192;
        bias_c[192 + u] = f2bf(in_elem(b_hh, u, f32));
    }
}

// Wcomb[l][k][g] = sum_j Wc[l][k][j]*w_ih[g][j], B-frag order
__global__ __launch_bounds__(64) void wcomb_kernel(
        const void* __restrict__ conv_w, const void* __restrict__ w_ih,
        unsigned short* __restrict__ wcomb, const int* __restrict__ flags) {
    int f32 = flags[0];
    int lane = threadIdx.x;
    int c = blockIdx.x;
    int l = blockIdx.y;
    int kb = c / 12, jt = c % 12;
    int quad = lane >> 4, l15 = lane & 15;
    int g = jt * 16 + l15;
    unsigned short* dst = wcomb + (size_t)l * 12288 + ((size_t)c * 64 + lane) * 8;
#pragma unroll
    for (int i = 0; i < 8; ++i) {
        int k = kb * 32 + quad * 8 + i;
        float acc = 0.0f;
        for (int j = 0; j < 64; ++j)
            acc += in_elem(conv_w, (size_t)l * 4096 + k * 64 + j, f32) *
                   in_elem(w_ih, (size_t)g * 64 + j, f32);
        dst[i] = f2bf(acc);
    }
}

// ============================ main pipeline ================================
template <int XF32>
DEVI void proj_in_body(const void* __restrict__ xr,
                       const unsigned short* __restrict__ wfrag,
                       unsigned short* __restrict__ h) {
    int wid = blockIdx.x * 4 + (threadIdx.x >> 6);
    if (wid >= ROW_TILES) return;
    int lane = threadIdx.x & 63;
    int l15 = lane & 15, quad = lane >> 4;
    int row0 = wid * 16;
    int arow = row0 + l15;

    f32x4 acc[4];
#pragma unroll
    for (int jt = 0; jt < 4; ++jt) acc[jt] = (f32x4)(0.0f);

#pragma unroll
    for (int kb = 0; kb < 8; ++kb) {
        short8 a;
        if (XF32)
            a = f32row_to_frag((const float*)xr + (size_t)arow * F_IN + kb * 32 + quad * 8);
        else
            a = *(const short8*)((const unsigned short*)xr + (size_t)arow * F_IN + kb * 32 + quad * 8);
#pragma unroll
        for (int jt = 0; jt < 4; ++jt) {
            short8 b = *(const short8*)(wfrag + (size_t)((kb * 4 + jt) * 64 + lane) * 8);
            acc[jt] = __builtin_amdgcn_mfma_f32_16x16x32_bf16(a, b, acc[jt], 0, 0, 0);
        }
    }
#pragma unroll
    for (int jt = 0; jt < 4; ++jt)
#pragma unroll
        for (int r = 0; r < 4; ++r)
            h[(size_t)(row0 + quad * 4 + r) * H_DIM + jt * 16 + l15] = f2bf(acc[jt][r]);
}

__global__ __launch_bounds__(256) void proj_in_kernel(
        const void* __restrict__ x,
        const unsigned short* __restrict__ wfrag,
        unsigned short* __restrict__ h,
        const int* __restrict__ flags) {
    if (flags[0]) proj_in_body<1>(x, wfrag, h);
    else          proj_in_body<0>(x, wfrag, h);
}

// ---------------------------------------------------------------------------
// Fused gather+GRU. hin read-only (double-buffered), hout written.
// Gather: node = row0 + it*4 + quad, lane covers channels 4*l15..+3 (uint2),
// 4 node-groups interleaved -> 16 independent lines in flight per wave.
// Agg tile staged via LDS [16][68] fp32 (16B-aligned frag reads).
// ---------------------------------------------------------------------------
__global__ __launch_bounds__(256) void gru_fused(
        const unsigned short* __restrict__ hin,
        unsigned short* __restrict__ hout,
        const int* __restrict__ rowptr,
        const int* __restrict__ counts,
        const int* __restrict__ esrc,
        const unsigned short* __restrict__ wcomb_l,
        const unsigned short* __restrict__ whh_c,
        const unsigned short* __restrict__ bias_c) {
    __shared__ float aggT[4][16][68];
    int warp = threadIdx.x >> 6;
    int lane = threadIdx.x & 63;
    int wid = blockIdx.x * 4 + warp;
    bool active = (wid < ROW_TILES);
    int wids = active ? wid : (ROW_TILES - 1);
    int l15 = lane & 15, quad = lane >> 4;
    int row0 = wids * 16;

    // ---- gather phase ----
    int st[4], dg[4];
    int mxd = 0;
#pragma unroll
    for (int it = 0; it < 4; ++it) {
        int n = row0 + it * 4 + quad;
        st[it] = rowptr[n];
        dg[it] = active ? counts[n] : 0;
        mxd = max(mxd, dg[it]);
    }
    f32x4 ac[4];
#pragma unroll
    for (int it = 0; it < 4; ++it) ac[it] = (f32x4)(0.0f);
    for (int i = 0; i < mxd; ++i) {
#pragma unroll
        for (int it = 0; it < 4; ++it) {
            if (i < dg[it]) {
                int s = esrc[st[it] + i];
                ushort4 u = *(const ushort4*)(hin + (size_t)s * H_DIM + l15 * 4);
                ac[it][0] += bf2f(u.x);
                ac[it][1] += bf2f(u.y);
                ac[it][2] += bf2f(u.z);
                ac[it][3] += bf2f(u.w);
            }
        }
    }
#pragma unroll
    for (int it = 0; it < 4; ++it)
        *(f32x4*)&aggT[warp][it * 4 + quad][l15 * 4] = ac[it];
    __syncthreads();

    // ---- GRU phase ----
    f32x4 gi[12], gh[12];
#pragma unroll
    for (int jt = 0; jt < 12; ++jt) { gi[jt] = (f32x4)(0.0f); gh[jt] = (f32x4)(0.0f); }

#pragma unroll
    for (int kb = 0; kb < 2; ++kb) {
        short8 aa;
#pragma unroll
        for (int i = 0; i < 8; ++i)
            aa[i] = (short)f2bf(aggT[warp][l15][kb * 32 + quad * 8 + i]);
        short8 ah = *(const short8*)(hin + (size_t)(row0 + l15) * H_DIM + kb * 32 + quad * 8);
#pragma unroll
        for (int jt = 0; jt < 12; ++jt) {
            short8 bi = *(const short8*)(wcomb_l + (size_t)((kb * 12 + jt) * 64 + lane) * 8);
            gi[jt] = __builtin_amdgcn_mfma_f32_16x16x32_bf16(aa, bi, gi[jt], 0, 0, 0);
            short8 bh = *(const short8*)(whh_c + (size_t)(jt * 16 + l15) * H_DIM + kb * 32 + quad * 8);
            gh[jt] = __builtin_amdgcn_mfma_f32_16x16x32_bf16(ah, bh, gh[jt], 0, 0, 0);
        }
    }

#pragma unroll
    for (int jc = 0; jc < 4; ++jc) {
        int j = jc * 16 + l15;
        float bir = bf2f(bias_c[j]),       bhr = bf2f(bias_c[192 + j]);
        float biz = bf2f(bias_c[64 + j]),  bhz = bf2f(bias_c[256 + j]);
        float bin = bf2f(bias_c[128 + j]), bhn = bf2f(bias_c[320 + j]);
#pragma unroll
        for (int r = 0; r < 4; ++r) {
            int row = row0 + quad * 4 + r;
            float xr = (gi[jc][r] + bir) + (gh[jc][r] + bhr);
            float xz = (gi[4 + jc][r] + biz) + (gh[4 + jc][r] + bhz);
            float in_ = gi[8 + jc][r] + bin;
            float hn_ = gh[8 + jc][r] + bhn;
            xr = fminf(fmaxf(xr, -30.0f), 30.0f);
            xz = fminf(fmaxf(xz, -30.0f), 30.0f);
            float rg = 1.0f / (1.0f + __expf(-xr));
            float zg = 1.0f / (1.0f + __expf(-xz));
            float na = in_ + rg * hn_;
            float ey = __expf(-2.0f * fabsf(na));          // (0,1] — safe tanh
            float th = (1.0f - ey) / (1.0f + ey);
            float nt = (na < 0.0f) ? -th : th;
            float ho = bf2f(hin[(size_t)row * H_DIM + j]);
            if (active)
                hout[(size_t)row * H_DIM + j] = f2bf((1.0f - zg) * nt + zg * ho);
        }
    }
}

// out = log_softmax(h @ W_out[64,40]); store fp32/bf16 per flags[0]
__global__ __launch_bounds__(256) void projout_kernel(
        const unsigned short* __restrict__ h,
        const unsigned short* __restrict__ wofrag,
        void* __restrict__ out,
        const int* __restrict__ flags) {
    int f32out = flags[0];
    int wid = blockIdx.x * 4 + (threadIdx.x >> 6);
    if (wid >= ROW_TILES) return;
    int lane = threadIdx.x & 63;
    int l15 = lane & 15, quad = lane >> 4;
    int row0 = wid * 16;
    int arow = row0 + l15;

    f32x4 acc[3];
#pragma unroll
    for (int jt = 0; jt < 3; ++jt) acc[jt] = (f32x4)(0.0f);

#pragma unroll
    for (int kb = 0; kb < 2; ++kb) {
        short8 a = *(const short8*)(h + (size_t)arow * H_DIM + kb * 32 + quad * 8);
#pragma unroll
        for (int jt = 0; jt < 3; ++jt) {
            short8 b = *(const short8*)(wofrag + (size_t)((kb * 3 + jt) * 64 + lane) * 8);
            acc[jt] = __builtin_amdgcn_mfma_f32_16x16x32_bf16(a, b, acc[jt], 0, 0, 0);
        }
    }

    float* of = (float*)out;
    unsigned short* ob = (unsigned short*)out;
    bool valid2 = (l15 < 8);
#pragma unroll
    for (int r = 0; r < 4; ++r) {
        int row = row0 + quad * 4 + r;
        float v0 = acc[0][r], v1 = acc[1][r], v2 = acc[2][r];
        float mx = fmaxf(v0, v1);
        if (valid2) mx = fmaxf(mx, v2);
#pragma unroll
        for (int d = 1; d < 16; d <<= 1) mx = fmaxf(mx, __shfl_xor(mx, d));
        float s = __expf(v0 - mx) + __expf(v1 - mx) + (valid2 ? __expf(v2 - mx) : 0.0f);
#pragma unroll
        for (int d = 1; d < 16; d <<= 1) s += __shfl_xor(s, d);
        float lg = mx + __logf(s);
        size_t o0 = (size_t)row * C_OUT + l15;
        if (f32out) {
            of[o0]      = v0 - lg;
            of[o0 + 16] = v1 - lg;
            if (valid2) of[o0 + 32] = v2 - lg;
        } else {
            ob[o0]      = f2bf(v0 - lg);
            ob[o0 + 16] = f2bf(v1 - lg);
            if (valid2) ob[o0 + 32] = f2bf(v2 - lg);
        }
    }
}

// ---------------------------------------------------------------------------
extern "C" void kernel_launch(void* const* d_in, const int* in_sizes, int n_in,
                              void* d_out, int out_size, void* d_ws, size_t ws_size,
                              hipStream_t stream) {
    const void* x      = d_in[0];
    const int*  ei     = (const int*)d_in[1];
    const void* w_in   = d_in[2];
    const void* w_out  = d_in[3];
    const void* conv_w = d_in[4];
    const void* w_ih   = d_in[5];
    const void* w_hh   = d_in[6];
    const void* b_ih   = d_in[7];
    const void* b_hh   = d_in[8];

    const int E   = in_sizes[1] / 2;
    const int nwg = (E + CH - 1) / CH;   // 147 for E=1.2M (<= 256 required)

    // workspace carve-up (256B aligned). Total ~38.4 MB.
    char* ws = (char*)d_ws;
    size_t off = 0;
    auto carve = [&](size_t bytes) {
        void* p = ws + off;
        off += (bytes + 255) & ~(size_t)255;
        return p;
    };
    int*            flags    = (int*)carve(256);
    unsigned short* h0       = (unsigned short*)carve((size_t)N_NODES * H_DIM * 2); // 12.8 MB
    unsigned short* h1       = (unsigned short*)carve((size_t)N_NODES * H_DIM * 2); // 12.8 MB
    int*            counts   = (int*)carve((size_t)N_NODES * 4);
    int*            rowptr   = (int*)carve((size_t)N_NODES * 4);
    int*            wgsorted = (int*)carve((size_t)nwg * CH * 4);                   // 4.8 MB
    int*            lbase_g  = (int*)carve((size_t)nwg * LB_STRIDE * 4);            // 0.46 MB
    int*            esrcP    = (int*)carve((size_t)NBUCK * BCAP * 4);               // 6.4 MB
    unsigned short* winfrag  = (unsigned short*)carve((size_t)16384 * 2);
    unsigned short* wcomb    = (unsigned short*)carve((size_t)4 * 12288 * 2);
    unsigned short* wofrag   = (unsigned short*)carve((size_t)3072 * 2);
    unsigned short* whh_c    = (unsigned short*)carve((size_t)12288 * 2);
    unsigned short* bias_c   = (unsigned short*)carve((size_t)384 * 2);

    // ---- probe ----
    detect_kernel<<<1, 64, 0, stream>>>(x, ei, flags);

    // ---- CSR build ----
    bucket_local<<<nwg, 256, 0, stream>>>(ei, E, flags, wgsorted, lbase_g);
    bucket_csr<<<NBUCK, 256, 0, stream>>>(wgsorted, lbase_g, nwg,
                                          rowptr, counts, esrcP);

    // ---- weight prep (merged) ----
    prep_misc<<<(16384 + 3072 + 12288 + 384 + 255) / 256, 256, 0, stream>>>(
        w_in, w_out, w_hh, b_ih, b_hh, winfrag, wofrag, whh_c, bias_c, flags);
    wcomb_kernel<<<dim3(24, 4), 64, 0, stream>>>(conv_w, w_ih, wcomb, flags);

    const int gblocks = (ROW_TILES + 3) / 4;  // 1563

    // ---- input projection ----
    proj_in_kernel<<<gblocks, 256, 0, stream>>>(x, winfrag, h0, flags);

    // ---- GGNN layers (double-buffered h) ----
    unsigned short* hin = h0;
    unsigned short* hout = h1;
    for (int l = 0; l < 4; ++l) {
        gru_fused<<<gblocks, 256, 0, stream>>>(hin, hout, rowptr, counts, esrcP,
                                               wcomb + (size_t)l * 12288, whh_c, bias_c);
        unsigned short* t = hin; hin = hout; hout = t;
    }

    // ---- output projection + log_softmax ----
    projout_kernel<<<gblocks, 256, 0, stream>>>(hin, wofrag, d_out, flags);
}

// Round 8
// 627.354 us; speedup vs baseline: 1.6135x; 1.6135x over previous
//
#include <hip/hip_runtime.h>

// ---------------------------------------------------------------------------
// GGNN on MI355X (gfx950). Runtime dtype probe (validated round 4): flags[0]=1
// -> fp32 float tensors + fp32 out; flags[1]=1 -> int64 edge_index.
// Intermediates canonical: h bf16 (in-place GRU update), agg bf16.
//
// Round-8: REVERT round-7 fusion (124 VGPR kernel ran gather at 17.8% occ ->
// 4x slower; latency-bound gather must live in its own 4-VGPR kernel).
// Keep: parallel bucket_csr, merged prep (now ONE prep_all kernel).
// New: gather_agg unrolled 8-deep (8 independent accumulators, ~20 VGPR,
// occupancy ~8 waves/SIMD) -> 2x outstanding cache lines per wave.
// Math (linearity): segment_sum((h@Wc)[src]) == segment_sum(h[src])@Wc;
//   (agg@Wc)@W_ih^T == agg@(Wc@W_ih^T) =: agg@Wcomb (built on device).
// ---------------------------------------------------------------------------

#define DEVI __device__ __forceinline__

typedef __attribute__((ext_vector_type(8))) short short8;
typedef __attribute__((ext_vector_type(4))) float f32x4;

constexpr int N_NODES   = 100000;
constexpr int F_IN      = 256;
constexpr int H_DIM     = 64;
constexpr int C_OUT     = 40;
constexpr int ROW_TILES = N_NODES / 16;             // 6250
constexpr int CH        = 8192;                     // edges per bucket_local wg
constexpr int NBUCK     = (N_NODES + 127) / 128;    // 782 buckets of 128 nodes
constexpr int LB_STRIDE = NBUCK + 1;                // +1 sentinel (wg total)
constexpr int BCAP      = 2048;                     // max edges/bucket (mean 1534)

DEVI float bf2f(unsigned short u) {
    unsigned v = ((unsigned)u) << 16;
    float f; __builtin_memcpy(&f, &v, 4); return f;
}
DEVI unsigned short f2bf(float f) {
    unsigned u; __builtin_memcpy(&u, &f, 4);
    unsigned r = u + 0x7FFFu + ((u >> 16) & 1u);   // round-to-nearest-even
    return (unsigned short)(r >> 16);
}
DEVI float in_elem(const void* p, size_t idx, int f32flag) {
    return f32flag ? ((const float*)p)[idx]
                   : bf2f(((const unsigned short*)p)[idx]);
}
DEVI short8 f32row_to_frag(const float* __restrict__ p) {
    const f32x4* q = (const f32x4*)p;
    f32x4 lo = q[0], hi = q[1];
    short8 a;
    a[0] = (short)f2bf(lo[0]); a[1] = (short)f2bf(lo[1]);
    a[2] = (short)f2bf(lo[2]); a[3] = (short)f2bf(lo[3]);
    a[4] = (short)f2bf(hi[0]); a[5] = (short)f2bf(hi[1]);
    a[6] = (short)f2bf(hi[2]); a[7] = (short)f2bf(hi[3]);
    return a;
}

// ---------------------------------------------------------------------------
__global__ void detect_kernel(const void* x, const int* ei, int* flags) {
    if (threadIdx.x != 0 || blockIdx.x != 0) return;
    const unsigned short* u = (const unsigned short*)x;
    int sane = 0;
    for (int i = 0; i < 256; ++i) {
        int e = (u[i] >> 7) & 0xFF;
        if (e >= 100 && e <= 145) sane++;
    }
    flags[0] = (sane < 230) ? 1 : 0;
    int zeros = 0;
    for (int i = 0; i < 64; ++i)
        if (ei[2 * i + 1] == 0) zeros++;
    flags[1] = (zeros >= 63) ? 1 : 0;
}

// ======================= CSR build: two-level sort =========================
__global__ __launch_bounds__(256) void bucket_local(
        const int* __restrict__ ei, int E, const int* __restrict__ flags,
        int* __restrict__ wgsorted,     // [nwg*CH]  packed (ldst<<17 | src)
        int* __restrict__ lbase_g) {    // [nwg*LB_STRIDE]
    __shared__ int hist[NBUCK];
    __shared__ int partial[256];
    __shared__ int staging[CH];
    int tid = threadIdx.x, wg = blockIdx.x;
    int i64 = flags[1];
    int base = wg * CH;
    int cnt_wg = min(CH, E - base);

    for (int i = tid; i < NBUCK; i += 256) hist[i] = 0;
    __syncthreads();
    for (int k = tid; k < cnt_wg; k += 256) {
        size_t e = (size_t)base + k;
        int d = i64 ? ei[2 * ((size_t)E + e)] : ei[(size_t)E + e];
        atomicAdd(&hist[d >> 7], 1);
    }
    __syncthreads();
    int i0 = 4 * tid;
    int e0 = (i0 + 0 < NBUCK) ? hist[i0 + 0] : 0;
    int e1 = (i0 + 1 < NBUCK) ? hist[i0 + 1] : 0;
    int e2 = (i0 + 2 < NBUCK) ? hist[i0 + 2] : 0;
    int e3 = (i0 + 3 < NBUCK) ? hist[i0 + 3] : 0;
    int s0 = e0, s1 = s0 + e1, s2 = s1 + e2, s3 = s2 + e3;
    __syncthreads();
    partial[tid] = s3;
    __syncthreads();
    for (int ofs = 1; ofs < 256; ofs <<= 1) {
        int add = (tid >= ofs) ? partial[tid - ofs] : 0;
        __syncthreads();
        partial[tid] += add;
        __syncthreads();
    }
    int pbase = (tid > 0) ? partial[tid - 1] : 0;
    if (i0 + 0 < NBUCK) hist[i0 + 0] = pbase;
    if (i0 + 1 < NBUCK) hist[i0 + 1] = pbase + s0;
    if (i0 + 2 < NBUCK) hist[i0 + 2] = pbase + s1;
    if (i0 + 3 < NBUCK) hist[i0 + 3] = pbase + s2;
    __syncthreads();
    int* lb = lbase_g + (size_t)wg * LB_STRIDE;
    for (int i = tid; i < NBUCK; i += 256) lb[i] = hist[i];
    if (tid == 0) lb[NBUCK] = cnt_wg;
    __syncthreads();
    for (int k = tid; k < cnt_wg; k += 256) {
        size_t e = (size_t)base + k;
        int s, d;
        if (i64) { s = ei[2 * e]; d = ei[2 * ((size_t)E + e)]; }
        else     { s = ei[e];     d = ei[(size_t)E + e]; }
        int pos = atomicAdd(&hist[d >> 7], 1);
        staging[pos] = ((d & 127) << 17) | s;     // src < 2^17
    }
    __syncthreads();
    for (int k = tid; k < cnt_wg; k += 256)
        wgsorted[(size_t)base + k] = staging[k];
}

__global__ __launch_bounds__(256) void bucket_csr(
        const int* __restrict__ wgsorted,
        const int* __restrict__ lbase_g,
        int nwg,
        int* __restrict__ rowptr,
        int* __restrict__ counts,
        int* __restrict__ esrc) {       // [NBUCK*BCAP] padded
    __shared__ int segincl[256];
    __shared__ int segbase[256];
    __shared__ int edata[BCAP];
    __shared__ int sout[BCAP];
    __shared__ int hist2[128];
    __shared__ int cur2[128];
    int tid = threadIdx.x, b = blockIdx.x;

    int lbv = 0, cntv = 0;
    if (tid < nwg) {
        const int* lb = lbase_g + (size_t)tid * LB_STRIDE;
        lbv  = lb[b];
        cntv = lb[b + 1] - lbv;
    }
    segbase[tid] = lbv;
    segincl[tid] = cntv;
    __syncthreads();
    for (int ofs = 1; ofs < 256; ofs <<= 1) {
        int add = (tid >= ofs) ? segincl[tid - ofs] : 0;
        __syncthreads();
        segincl[tid] += add;
        __syncthreads();
    }
    int tot = min(segincl[255], BCAP);   // 13-sigma margin; clamp = visible-fail
    for (int i = tid; i < tot; i += 256) {
        int lo = 0, hi = 255;
        while (lo < hi) {
            int mid = (lo + hi) >> 1;
            if (segincl[mid] > i) hi = mid; else lo = mid + 1;
        }
        int excl = (lo > 0) ? segincl[lo - 1] : 0;
        edata[i] = wgsorted[(size_t)lo * CH + segbase[lo] + (i - excl)];
    }
    if (tid < 128) hist2[tid] = 0;
    __syncthreads();
    for (int i = tid; i < tot; i += 256) atomicAdd(&hist2[edata[i] >> 17], 1);
    __syncthreads();
    if (tid < 128) cur2[tid] = hist2[tid];
    __syncthreads();
    for (int ofs = 1; ofs < 128; ofs <<= 1) {
        int add = 0;
        if (tid < 128 && tid >= ofs) add = cur2[tid - ofs];
        __syncthreads();
        if (tid < 128) cur2[tid] += add;
        __syncthreads();
    }
    int nodeexcl = 0;
    if (tid < 128) nodeexcl = (tid > 0) ? cur2[tid - 1] : 0;
    __syncthreads();
    if (tid < 128) {
        int node = b * 128 + tid;
        if (node < N_NODES) {
            counts[node] = hist2[tid];
            rowptr[node] = b * BCAP + nodeexcl;
        }
        cur2[tid] = nodeexcl;
    }
    __syncthreads();
    for (int i = tid; i < tot; i += 256) {
        int p = edata[i];
        int pos = atomicAdd(&cur2[p >> 17], 1);
        sout[pos] = p & 0x1FFFF;
    }
    __syncthreads();
    for (int i = tid; i < tot; i += 256)
        esrc[(size_t)b * BCAP + i] = sout[i];
}

// ============================ weight prep (one kernel) =====================
// t-ranges: winfrag 16384 | wofrag 3072 | whh 12288 | b_ih 192 | b_hh 192 |
//           wcomb 4*24*64 = 6144 (each thread: 8 outputs x 64-MAC dot)
__global__ void prep_all(const void* __restrict__ w_in,
                         const void* __restrict__ w_out,
                         const void* __restrict__ w_hh,
                         const void* __restrict__ b_ih,
                         const void* __restrict__ b_hh,
                         const void* __restrict__ conv_w,
                         const void* __restrict__ w_ih,
                         unsigned short* __restrict__ winfrag,
                         unsigned short* __restrict__ wofrag,
                         unsigned short* __restrict__ whh_c,
                         unsigned short* __restrict__ bias_c,
                         unsigned short* __restrict__ wcomb,
                         const int* __restrict__ flags) {
    int f32 = flags[0];
    int t = blockIdx.x * blockDim.x + threadIdx.x;
    if (t < 16384) {
        int i = t & 7, lane = (t >> 3) & 63, jt = (t >> 9) & 3, kb = t >> 11;
        int k = kb * 32 + ((lane >> 4) << 3) + i;
        int col = jt * 16 + (lane & 15);
        winfrag[t] = f2bf(in_elem(w_in, (size_t)k * 64 + col, f32));
    } else if (t < 19456) {
        int u = t - 16384;
        int i = u & 7, lane = (u >> 3) & 63;
        int jt = (u >> 9) % 3, kb = u / 1536;
        int k = kb * 32 + ((lane >> 4) << 3) + i;
        int col = jt * 16 + (lane & 15);
        wofrag[u] = (col < 40) ? f2bf(in_elem(w_out, (size_t)k * 40 + col, f32))
                               : (unsigned short)0;
    } else if (t < 31744) {
        int u = t - 19456;
        whh_c[u] = f2bf(in_elem(w_hh, u, f32));
    } else if (t < 31936) {
        int u = t - 31744;
        bias_c[u] = f2bf(in_elem(b_ih, u, f32));
    } else if (t < 32128) {
        int u = t - 31936;
        bias_c[192 + u] = f2bf(in_elem(b_hh, u, f32));
    } else if (t < 32128 + 6144) {
        int u = t - 32128;
        int lane = u & 63;
        int c = (u >> 6) % 24;       // kb*12 + jt
        int l = u / 1536;            // layer
        int kb = c / 12, jt = c % 12;
        int quad = lane >> 4, l15 = lane & 15;
        int g = jt * 16 + l15;
        unsigned short* dst = wcomb + (size_t)l * 12288 + ((size_t)c * 64 + lane) * 8;
#pragma unroll
        for (int i = 0; i < 8; ++i) {
            int k = kb * 32 + quad * 8 + i;
            float acc = 0.0f;
            for (int j = 0; j < 64; ++j)
                acc += in_elem(conv_w, (size_t)l * 4096 + k * 64 + j, f32) *
                       in_elem(w_ih, (size_t)g * 64 + j, f32);
            dst[i] = f2bf(acc);
        }
    }
}

// ============================ main pipeline ================================
template <int XF32>
DEVI void proj_in_body(const void* __restrict__ xr,
                       const unsigned short* __restrict__ wfrag,
                       unsigned short* __restrict__ h) {
    int wid = blockIdx.x * 4 + (threadIdx.x >> 6);
    if (wid >= ROW_TILES) return;
    int lane = threadIdx.x & 63;
    int l15 = lane & 15, quad = lane >> 4;
    int row0 = wid * 16;
    int arow = row0 + l15;

    f32x4 acc[4];
#pragma unroll
    for (int jt = 0; jt < 4; ++jt) acc[jt] = (f32x4)(0.0f);

#pragma unroll
    for (int kb = 0; kb < 8; ++kb) {
        short8 a;
        if (XF32)
            a = f32row_to_frag((const float*)xr + (size_t)arow * F_IN + kb * 32 + quad * 8);
        else
            a = *(const short8*)((const unsigned short*)xr + (size_t)arow * F_IN + kb * 32 + quad * 8);
#pragma unroll
        for (int jt = 0; jt < 4; ++jt) {
            short8 b = *(const short8*)(wfrag + (size_t)((kb * 4 + jt) * 64 + lane) * 8);
            acc[jt] = __builtin_amdgcn_mfma_f32_16x16x32_bf16(a, b, acc[jt], 0, 0, 0);
        }
    }
#pragma unroll
    for (int jt = 0; jt < 4; ++jt)
#pragma unroll
        for (int r = 0; r < 4; ++r)
            h[(size_t)(row0 + quad * 4 + r) * H_DIM + jt * 16 + l15] = f2bf(acc[jt][r]);
}

__global__ __launch_bounds__(256) void proj_in_kernel(
        const void* __restrict__ x,
        const unsigned short* __restrict__ wfrag,
        unsigned short* __restrict__ h,
        const int* __restrict__ flags) {
    if (flags[0]) proj_in_body<1>(x, wfrag, h);
    else          proj_in_body<0>(x, wfrag, h);
}

// aggB[n][j] = sum_{e: dst=n} h[src(e)][j] — one wave/node, lane = channel.
// 8 independent accumulators (8 lines in flight/wave) at ~20 VGPR so
// occupancy stays ~8 waves/SIMD. Round-7 lesson: this must NOT share a
// kernel with the MFMA phase (124 VGPR -> 17.8% occ -> 4x slower gather).
__global__ __launch_bounds__(256) void gather_agg(
        const unsigned short* __restrict__ h,
        const int* __restrict__ rowptr,
        const int* __restrict__ counts,
        const int* __restrict__ esrc,
        unsigned short* __restrict__ aggB) {
    int n = blockIdx.x * 4 + (threadIdx.x >> 6);
    if (n >= N_NODES) return;
    int j = threadIdx.x & 63;
    int start = rowptr[n];
    int deg   = counts[n];
    float a0 = 0.f, a1 = 0.f, a2 = 0.f, a3 = 0.f;
    float a4 = 0.f, a5 = 0.f, a6 = 0.f, a7 = 0.f;
    int i = 0;
    for (; i + 8 <= deg; i += 8) {
        int s0 = esrc[start + i],     s1 = esrc[start + i + 1];
        int s2 = esrc[start + i + 2], s3 = esrc[start + i + 3];
        int s4 = esrc[start + i + 4], s5 = esrc[start + i + 5];
        int s6 = esrc[start + i + 6], s7 = esrc[start + i + 7];
        a0 += bf2f(h[(size_t)s0 * H_DIM + j]);
        a1 += bf2f(h[(size_t)s1 * H_DIM + j]);
        a2 += bf2f(h[(size_t)s2 * H_DIM + j]);
        a3 += bf2f(h[(size_t)s3 * H_DIM + j]);
        a4 += bf2f(h[(size_t)s4 * H_DIM + j]);
        a5 += bf2f(h[(size_t)s5 * H_DIM + j]);
        a6 += bf2f(h[(size_t)s6 * H_DIM + j]);
        a7 += bf2f(h[(size_t)s7 * H_DIM + j]);
    }
    for (; i + 4 <= deg; i += 4) {
        int s0 = esrc[start + i],     s1 = esrc[start + i + 1];
        int s2 = esrc[start + i + 2], s3 = esrc[start + i + 3];
        a0 += bf2f(h[(size_t)s0 * H_DIM + j]);
        a1 += bf2f(h[(size_t)s1 * H_DIM + j]);
        a2 += bf2f(h[(size_t)s2 * H_DIM + j]);
        a3 += bf2f(h[(size_t)s3 * H_DIM + j]);
    }
    for (; i < deg; ++i)
        a0 += bf2f(h[(size_t)esrc[start + i] * H_DIM + j]);
    aggB[(size_t)n * H_DIM + j] = f2bf(((a0 + a1) + (a2 + a3)) + ((a4 + a5) + (a6 + a7)));
}

// Fused GRUCell, h in place (race-free: each 16-row block owned by one wave)
__global__ __launch_bounds__(256) void gru_kernel(
        const unsigned short* __restrict__ aggB,
        unsigned short* __restrict__ h,
        const unsigned short* __restrict__ wcomb_l,
        const unsigned short* __restrict__ whh_c,
        const unsigned short* __restrict__ bias_c) {
    int wid = blockIdx.x * 4 + (threadIdx.x >> 6);
    if (wid >= ROW_TILES) return;
    int lane = threadIdx.x & 63;
    int l15 = lane & 15, quad = lane >> 4;
    int row0 = wid * 16;
    int arow = row0 + l15;

    f32x4 gi[12], gh[12];
#pragma unroll
    for (int jt = 0; jt < 12; ++jt) { gi[jt] = (f32x4)(0.0f); gh[jt] = (f32x4)(0.0f); }

#pragma unroll
    for (int kb = 0; kb < 2; ++kb) {
        short8 aa = *(const short8*)(aggB + (size_t)arow * H_DIM + kb * 32 + quad * 8);
        short8 ah = *(const short8*)(h + (size_t)arow * H_DIM + kb * 32 + quad * 8);
#pragma unroll
        for (int jt = 0; jt < 12; ++jt) {
            short8 bi = *(const short8*)(wcomb_l + (size_t)((kb * 12 + jt) * 64 + lane) * 8);
            gi[jt] = __builtin_amdgcn_mfma_f32_16x16x32_bf16(aa, bi, gi[jt], 0, 0, 0);
            short8 bh = *(const short8*)(whh_c + (size_t)(jt * 16 + l15) * H_DIM + kb * 32 + quad * 8);
            gh[jt] = __builtin_amdgcn_mfma_f32_16x16x32_bf16(ah, bh, gh[jt], 0, 0, 0);
        }
    }

#pragma unroll
    for (int jc = 0; jc < 4; ++jc) {
        int j = jc * 16 + l15;
        float bir = bf2f(bias_c[j]),       bhr = bf2f(bias_c[192 + j]);
        float biz = bf2f(bias_c[64 + j]),  bhz = bf2f(bias_c[256 + j]);
        float bin = bf2f(bias_c[128 + j]), bhn = bf2f(bias_c[320 + j]);
#pragma unroll
        for (int r = 0; r < 4; ++r) {
            int row = row0 + quad * 4 + r;
            float xr = (gi[jc][r] + bir) + (gh[jc][r] + bhr);
            float xz = (gi[4 + jc][r] + biz) + (gh[4 + jc][r] + bhz);
            float in_ = gi[8 + jc][r] + bin;
            float hn_ = gh[8 + jc][r] + bhn;
            xr = fminf(fmaxf(xr, -30.0f), 30.0f);
            xz = fminf(fmaxf(xz, -30.0f), 30.0f);
            float rg = 1.0f / (1.0f + __expf(-xr));
            float zg = 1.0f / (1.0f + __expf(-xz));
            float na = in_ + rg * hn_;
            float ey = __expf(-2.0f * fabsf(na));          // (0,1] — safe tanh
            float th = (1.0f - ey) / (1.0f + ey);
            float nt = (na < 0.0f) ? -th : th;
            float ho = bf2f(h[(size_t)row * H_DIM + j]);
            h[(size_t)row * H_DIM + j] = f2bf((1.0f - zg) * nt + zg * ho);
        }
    }
}

// out = log_softmax(h @ W_out[64,40]); store fp32/bf16 per flags[0]
__global__ __launch_bounds__(256) void projout_kernel(
        const unsigned short* __restrict__ h,
        const unsigned short* __restrict__ wofrag,
        void* __restrict__ out,
        const int* __restrict__ flags) {
    int f32out = flags[0];
    int wid = blockIdx.x * 4 + (threadIdx.x >> 6);
    if (wid >= ROW_TILES) return;
    int lane = threadIdx.x & 63;
    int l15 = lane & 15, quad = lane >> 4;
    int row0 = wid * 16;
    int arow = row0 + l15;

    f32x4 acc[3];
#pragma unroll
    for (int jt = 0; jt < 3; ++jt) acc[jt] = (f32x4)(0.0f);

#pragma unroll
    for (int kb = 0; kb < 2; ++kb) {
        short8 a = *(const short8*)(h + (size_t)arow * H_DIM + kb * 32 + quad * 8);
#pragma unroll
        for (int jt = 0; jt < 3; ++jt) {
            short8 b = *(const short8*)(wofrag + (size_t)((kb * 3 + jt) * 64 + lane) * 8);
            acc[jt] = __builtin_amdgcn_mfma_f32_16x16x32_bf16(a, b, acc[jt], 0, 0, 0);
        }
    }

    float* of = (float*)out;
    unsigned short* ob = (unsigned short*)out;
    bool valid2 = (l15 < 8);
#pragma unroll
    for (int r = 0; r < 4; ++r) {
        int row = row0 + quad * 4 + r;
        float v0 = acc[0][r], v1 = acc[1][r], v2 = acc[2][r];
        float mx = fmaxf(v0, v1);
        if (valid2) mx = fmaxf(mx, v2);
#pragma unroll
        for (int d = 1; d < 16; d <<= 1) mx = fmaxf(mx, __shfl_xor(mx, d));
        float s = __expf(v0 - mx) + __expf(v1 - mx) + (valid2 ? __expf(v2 - mx) : 0.0f);
#pragma unroll
        for (int d = 1; d < 16; d <<= 1) s += __shfl_xor(s, d);
        float lg = mx + __logf(s);
        size_t o0 = (size_t)row * C_OUT + l15;
        if (f32out) {
            of[o0]      = v0 - lg;
            of[o0 + 16] = v1 - lg;
            if (valid2) of[o0 + 32] = v2 - lg;
        } else {
            ob[o0]      = f2bf(v0 - lg);
            ob[o0 + 16] = f2bf(v1 - lg);
            if (valid2) ob[o0 + 32] = f2bf(v2 - lg);
        }
    }
}

// ---------------------------------------------------------------------------
extern "C" void kernel_launch(void* const* d_in, const int* in_sizes, int n_in,
                              void* d_out, int out_size, void* d_ws, size_t ws_size,
                              hipStream_t stream) {
    const void* x      = d_in[0];
    const int*  ei     = (const int*)d_in[1];
    const void* w_in   = d_in[2];
    const void* w_out  = d_in[3];
    const void* conv_w = d_in[4];
    const void* w_ih   = d_in[5];
    const void* w_hh   = d_in[6];
    const void* b_ih   = d_in[7];
    const void* b_hh   = d_in[8];

    const int E   = in_sizes[1] / 2;
    const int nwg = (E + CH - 1) / CH;   // 147 for E=1.2M (<= 256 required)

    // workspace carve-up (256B aligned). Total ~38.4 MB.
    char* ws = (char*)d_ws;
    size_t off = 0;
    auto carve = [&](size_t bytes) {
        void* p = ws + off;
        off += (bytes + 255) & ~(size_t)255;
        return p;
    };
    int*            flags    = (int*)carve(256);
    unsigned short* aggB     = (unsigned short*)carve((size_t)N_NODES * H_DIM * 2); // 12.8 MB
    unsigned short* hbuf     = (unsigned short*)carve((size_t)N_NODES * H_DIM * 2); // 12.8 MB
    int*            counts   = (int*)carve((size_t)N_NODES * 4);
    int*            rowptr   = (int*)carve((size_t)N_NODES * 4);
    int*            wgsorted = (int*)carve((size_t)nwg * CH * 4);                   // 4.8 MB
    int*            lbase_g  = (int*)carve((size_t)nwg * LB_STRIDE * 4);            // 0.46 MB
    int*            esrcP    = (int*)carve((size_t)NBUCK * BCAP * 4);               // 6.4 MB
    unsigned short* winfrag  = (unsigned short*)carve((size_t)16384 * 2);
    unsigned short* wcomb    = (unsigned short*)carve((size_t)4 * 12288 * 2);
    unsigned short* wofrag   = (unsigned short*)carve((size_t)3072 * 2);
    unsigned short* whh_c    = (unsigned short*)carve((size_t)12288 * 2);
    unsigned short* bias_c   = (unsigned short*)carve((size_t)384 * 2);

    // ---- probe ----
    detect_kernel<<<1, 64, 0, stream>>>(x, ei, flags);

    // ---- CSR build ----
    bucket_local<<<nwg, 256, 0, stream>>>(ei, E, flags, wgsorted, lbase_g);
    bucket_csr<<<NBUCK, 256, 0, stream>>>(wgsorted, lbase_g, nwg,
                                          rowptr, counts, esrcP);

    // ---- weight prep (single kernel) ----
    prep_all<<<(32128 + 6144 + 255) / 256, 256, 0, stream>>>(
        w_in, w_out, w_hh, b_ih, b_hh, conv_w, w_ih,
        winfrag, wofrag, whh_c, bias_c, wcomb, flags);

    const int gblocks = (ROW_TILES + 3) / 4;  // 1563
    const int nblocks = N_NODES / 4;          // 25000

    // ---- input projection ----
    proj_in_kernel<<<gblocks, 256, 0, stream>>>(x, winfrag, hbuf, flags);

    // ---- GGNN layers ----
    for (int l = 0; l < 4; ++l) {
        gather_agg<<<nblocks, 256, 0, stream>>>(hbuf, rowptr, counts, esrcP, aggB);
        gru_kernel<<<gblocks, 256, 0, stream>>>(aggB, hbuf, wcomb + (size_t)l * 12288,
                                                whh_c, bias_c);
    }

    // ---- output projection + log_softmax ----
    projout_kernel<<<gblocks, 256, 0, stream>>>(hbuf, wofrag, d_out, flags);
}